// Round 11
// baseline (132.545 us; speedup 1.0000x reference)
//
#include <hip/hip_runtime.h>

#define NB   4
#define H_IN 14
#define W_IN 14
#define FIN  32
#define DI   8
#define F    32
#define C    288   // 3*3*32
#define DO   16
#define HO   12
#define WO   12
#define NPOS (NB*HO*WO)   // 576
#define EPS  1e-7f

#define CH   32            // c-chunks processed by kern2w waves (9 c's each)
#define CHB  (CH/2)        // 16 merged chunks in part2 (pairs merged in-block)
#define CC   (C/CH)        // 9
#define GP   2             // positions per WAVE (R3/R7-proven sweet spot)
#define GRID2 (CHB*(NPOS/GP)/4) // 1152 blocks x 512 thr: 4 pos-groups x 2 chunks

#define KTOT  (C*DI)       // 2304 = K of the cent1 GEMM
#define KHALF 1152         // K/2 per kernM1 block (split-K)
#define KPADH 1156         // LDS row pad: 578 words % 32 = 2 -> 2-way (free)

#define W2H_BYTES  ((size_t)F*C*DO*DI*2)       // 2,359,296  (transposed, kern2)
#define WH_BYTES   ((size_t)F*C*DO*DI*2)       // 2,359,296  (orig layout, MFMA B)
#define PH_BYTES   ((size_t)NPOS*KTOT*2)       // 2,654,208  (patch matrix fp16)
#define PART_BYTES ((size_t)CHB*NPOS*F*DO*4)   // 18,874,368 (part2 fp32, [chb][pos][f][o])
#define OUT1P_BYTES ((size_t)2*NPOS*F*DO*4)    // 2,359,296  (K-half partials, pre-squash)

#define CVT_W   576        // fused W2h+Wh blocks (single Wt read)
#define CVT_PH  648        // 165888 uint4
#define CVT_GRID (CVT_W + CVT_PH)

typedef _Float16 h2 __attribute__((ext_vector_type(2)));
typedef _Float16 h8v __attribute__((ext_vector_type(8)));
typedef float    f4v __attribute__((ext_vector_type(4)));

__device__ __forceinline__ unsigned int pack2(float a, float b) {
    h2 v; v.x = (_Float16)a; v.y = (_Float16)b;
    return __builtin_bit_cast(unsigned int, v);
}

// 8-term fp16 dot with fp32 accumulate
__device__ __forceinline__ float dot8h(const uint4 w, const uint4 v, float acc) {
#if __has_builtin(__builtin_amdgcn_fdot2)
    acc = __builtin_amdgcn_fdot2(__builtin_bit_cast(h2, w.x), __builtin_bit_cast(h2, v.x), acc, false);
    acc = __builtin_amdgcn_fdot2(__builtin_bit_cast(h2, w.y), __builtin_bit_cast(h2, v.y), acc, false);
    acc = __builtin_amdgcn_fdot2(__builtin_bit_cast(h2, w.z), __builtin_bit_cast(h2, v.z), acc, false);
    acc = __builtin_amdgcn_fdot2(__builtin_bit_cast(h2, w.w), __builtin_bit_cast(h2, v.w), acc, false);
#else
    const h2 w0 = __builtin_bit_cast(h2, w.x), v0 = __builtin_bit_cast(h2, v.x);
    const h2 w1 = __builtin_bit_cast(h2, w.y), v1 = __builtin_bit_cast(h2, v.y);
    const h2 w2 = __builtin_bit_cast(h2, w.z), v2 = __builtin_bit_cast(h2, v.z);
    const h2 w3 = __builtin_bit_cast(h2, w.w), v3 = __builtin_bit_cast(h2, v.w);
    acc += (float)w0.x*(float)v0.x + (float)w0.y*(float)v0.y
         + (float)w1.x*(float)v1.x + (float)w1.y*(float)v1.y
         + (float)w2.x*(float)v2.x + (float)w2.y*(float)v2.y
         + (float)w3.x*(float)v3.x + (float)w3.y*(float)v3.y;
#endif
    return acc;
}

__device__ __forceinline__ int xbase_of(int pos) {
    const int b = pos/(HO*WO), rem = pos%(HO*WO), ho = rem/WO, wo = rem%WO;
    return ((b*H_IN + ho)*W_IN + wo)*FIN*DI;
}

__device__ __forceinline__ int coff_of(int c) {
    const int slab = c >> 5, fin = c & 31;
    const int kh = slab/3, kw = slab%3;
    return (kh*W_IN + kw)*FIN*DI + fin*DI;
}

// ---- conversion (single Wt read feeds BOTH Wh and W2h) ------------------------
__global__ __launch_bounds__(256) void kernConv(const float* __restrict__ Wt,
                                                const float* __restrict__ x,
                                                unsigned short* __restrict__ W2h,
                                                unsigned short* __restrict__ Wh,
                                                unsigned short* __restrict__ Ph) {
    const int b = blockIdx.x;
    if (b < CVT_W) {                   // one coalesced Wt read -> Wh copy + W2h transpose
        const int idx = b*256 + threadIdx.x;       // linear over Wt rows (f*C+c)*DO+o
        const float* src = Wt + (size_t)idx*8;     // coalesced read
        const float4 a = *(const float4*)src;
        const float4 bb = *(const float4*)(src + 4);
        uint4 r;
        r.x = pack2(a.x, a.y);   r.y = pack2(a.z, a.w);
        r.z = pack2(bb.x, bb.y); r.w = pack2(bb.z, bb.w);
        ((uint4*)Wh)[idx] = r;                         // same-layout copy
        const int o = idx & 15;
        const int c = (idx >> 4) % C;
        const int f = idx / (C*DO);
        ((uint4*)W2h)[(size_t)(c*DO + o)*F + f] = r;   // scattered write (L2 absorbs)
    } else {                           // Ph[pos][c*8+i]
        const int pc = (b - CVT_W)*256 + threadIdx.x;  // 165888
        const int pos = pc / C, c = pc % C;
        const float* src = x + xbase_of(pos) + coff_of(c);
        const float4 a = *(const float4*)src;
        const float4 bb = *(const float4*)(src + 4);
        uint4 r;
        r.x = pack2(a.x, a.y);   r.y = pack2(a.z, a.w);
        r.z = pack2(bb.x, bb.y); r.w = pack2(bb.z, bb.w);
        ((uint4*)Ph)[pc] = r;
    }
}

// ---- kernM1: cent1 GEMM via MFMA -> raw K-half partials (R7-proven split-K). --
__global__ __launch_bounds__(256) void kernM1(const unsigned short* __restrict__ Ph,
                                              const unsigned short* __restrict__ Wh,
                                              float* __restrict__ out1p)
{
    __shared__ unsigned short As[16][KPADH];      // 36,992 B

    const int tid  = threadIdx.x;
    const int lane = tid & 63;
    const int wv   = tid >> 6;                    // 0..3
    const int ks   = blockIdx.x & 1;              // K-half
    const int fg   = (blockIdx.x >> 1) & 7;       // 0..7
    const int pt   = blockIdx.x >> 4;             // 0..35
    const int f    = wv*8 + fg;                   // all 32 f covered
    const int pos0 = pt*16;
    const int n    = lane & 15, q = lane >> 4;

    // stage half-K A-tile: 2304 uint4, 9 per thread, coalesced
    #pragma unroll
    for (int r = 0; r < 9; ++r) {
        const int linear = r*256 + tid;
        const int row = linear / 144, col = linear % 144;   // 144 uint4 per row
        const uint4 v = *(const uint4*)(Ph + (size_t)(pos0 + row)*KTOT + ks*KHALF + col*8);
        *(uint4*)&As[row][col*8] = v;
    }
    __syncthreads();

    const unsigned short* pa = &As[n][q*8];                                 // A: m=lane&15
    const unsigned short* pb = Wh + ((size_t)(f*C + ks*144 + q)*DO + n)*DI; // B: n=lane&15

    f4v acc0 = {0.f,0.f,0.f,0.f}, acc1 = {0.f,0.f,0.f,0.f};
    #pragma unroll 4
    for (int s = 0; s < 36; s += 2) {             // 18 steps, 2 chains
        const h8v a0 = *(const h8v*)(pa + s*32);
        const h8v b0 = *(const h8v*)(pb + (size_t)s*4*DO*DI);
        const h8v a1 = *(const h8v*)(pa + (s+1)*32);
        const h8v b1 = *(const h8v*)(pb + (size_t)(s+1)*4*DO*DI);
        acc0 = __builtin_amdgcn_mfma_f32_16x16x32_f16(a0, b0, acc0, 0, 0, 0);
        acc1 = __builtin_amdgcn_mfma_f32_16x16x32_f16(a1, b1, acc1, 0, 0, 0);
    }

    // write raw partials (no reduction, no squash)
    #pragma unroll
    for (int r = 0; r < 4; ++r) {
        out1p[((size_t)ks*NPOS + pos0 + q*4 + r)*512 + f*DO + n] = acc0[r] + acc1[r];
    }
}

// ---- kern2w: routing iter 2 -- paired-chunk blocks (R11). ---------------------
// 512 threads = 8 waves = 4 pairs. Pair (wv, wv+4): SAME positions, even/odd
// c-chunk (9 c's each; CH=32 internally). Inner body is the R7/R10-verified
// 8-o map VERBATIM. Upper waves publish acc via lane-major LDS red[4][16][64]
// (conflict-free) + ONE barrier; lower waves add + store -> part2 keeps CHB=16
// chunks (18.9 MB, kern3 unchanged). 9216 waves (R8's occupancy win) WITHOUT
// R8's part2 doubling. Each LDS slot written by exactly one lane: deterministic.
// writes part2[chb][pos][f][o] fp32
__global__ __launch_bounds__(512) void kern2w(const unsigned short* __restrict__ Ph,
                                              const unsigned short* __restrict__ W2h,
                                              const float* __restrict__ out1p,
                                              float* __restrict__ part2)
{
    __shared__ float red[4][16][64];          // 16 KB, lane-major

    const int tid  = threadIdx.x;
    const int lane = tid & 63;
    const int wv   = tid >> 6;                // 0..7
    const int pr   = wv & 3;                  // pair index -> position group
    const int hi   = wv >> 2;                 // 0 = even chunk, 1 = odd chunk
    const int f    = lane & 31;
    const int og   = lane >> 5;               // 0/1
    const int o0   = og*8;

    const int chb  = blockIdx.x & (CHB-1);    // merged-chunk id (part2 index)
    const int gq   = blockIdx.x >> 4;         // 0..71
    const int pos0 = __builtin_amdgcn_readfirstlane(gq*4 + pr)*GP;

    const int c0 = (2*chb + hi)*CC;           // this wave's 9-c range
    const uint4* W2h4 = (const uint4*)W2h;

    // u[k][p] = squash(cent1)[pos][f][o0+k], cent1 = (half0+half1)/32
    float u[8][GP];
    #pragma unroll
    for (int p = 0; p < GP; ++p) {
        const float* up0 = out1p + (size_t)(pos0 + p)*512 + f*DO + o0;
        const float* up1 = up0 + (size_t)NPOS*512;
        const float4 a0 = *(const float4*)up0;
        const float4 b0 = *(const float4*)(up0 + 4);
        const float4 a1 = *(const float4*)up1;
        const float4 b1 = *(const float4*)(up1 + 4);
        float ur[8];
        ur[0]=(a0.x+a1.x)*(1.f/32.f); ur[1]=(a0.y+a1.y)*(1.f/32.f);
        ur[2]=(a0.z+a1.z)*(1.f/32.f); ur[3]=(a0.w+a1.w)*(1.f/32.f);
        ur[4]=(b0.x+b1.x)*(1.f/32.f); ur[5]=(b0.y+b1.y)*(1.f/32.f);
        ur[6]=(b0.z+b1.z)*(1.f/32.f); ur[7]=(b0.w+b1.w)*(1.f/32.f);
        float sq = 0.f;
        #pragma unroll
        for (int k = 0; k < 8; ++k) sq += ur[k]*ur[k];
        sq += __shfl_xor(sq, 32);             // full 16-o norm
        const float sc = (sq/(1.f + sq)) * rsqrtf(sq + EPS);
        #pragma unroll
        for (int k = 0; k < 8; ++k) u[k][p] = ur[k]*sc;
    }

    float acc[8][GP];
    #pragma unroll
    for (int k = 0; k < 8; ++k)
        #pragma unroll
        for (int p = 0; p < GP; ++p) acc[k][p] = 0.f;

    #pragma unroll 1
    for (int cl = 0; cl < CC; ++cl) {
        const int c = c0 + cl;

        // patch vectors: wave-uniform -> scalar loads
        uint4 xv[GP];
        #pragma unroll
        for (int p = 0; p < GP; ++p)
            xv[p] = *(const uint4*)(Ph + (size_t)(pos0 + p)*KTOT + c*DI);

        // preds for my 8 o's, all GP positions
        float pred[8][GP];
        #pragma unroll
        for (int k = 0; k < 8; ++k) {
            const uint4 w = W2h4[(size_t)(c*DO + o0 + k)*F + f];
            #pragma unroll
            for (int p = 0; p < GP; ++p) pred[k][p] = dot8h(w, xv[p], 0.f);
        }

        // per position: agreement (o-sum via xor-32), NO-MAX softmax over f
        #pragma unroll
        for (int p = 0; p < GP; ++p) {
            float ap = 0.f;
            #pragma unroll
            for (int k = 0; k < 8; ++k) ap += pred[k][p]*u[k][p];
            ap += __shfl_xor(ap, 32);          // both halves now hold full agr

            const float e = __expf(ap);        // |ap| small: safe without max-sub
            float s = e;
            s += __shfl_xor(s, 1);
            s += __shfl_xor(s, 2);
            s += __shfl_xor(s, 4);
            s += __shfl_xor(s, 8);
            s += __shfl_xor(s, 16);
            const float cc = e / s;

            #pragma unroll
            for (int k = 0; k < 8; ++k) acc[k][p] += cc*pred[k][p];
        }
    }

    // merge odd-chunk partials into even-chunk waves via LDS, then store
    if (hi) {
        #pragma unroll
        for (int k = 0; k < 8; ++k)
            #pragma unroll
            for (int p = 0; p < GP; ++p)
                red[pr][k*GP + p][lane] = acc[k][p];
    }
    __syncthreads();
    if (!hi) {
        #pragma unroll
        for (int k = 0; k < 8; ++k)
            #pragma unroll
            for (int p = 0; p < GP; ++p)
                acc[k][p] += red[pr][k*GP + p][lane];

        #pragma unroll
        for (int p = 0; p < GP; ++p) {
            float* dst = part2 + ((size_t)(chb*NPOS + pos0 + p)*F + f)*DO + o0;
            float4 s0, s1;
            s0.x=acc[0][p]; s0.y=acc[1][p]; s0.z=acc[2][p]; s0.w=acc[3][p];
            s1.x=acc[4][p]; s1.y=acc[5][p]; s1.z=acc[6][p]; s1.w=acc[7][p];
            *(float4*)dst = s0;
            *(float4*)(dst + 4) = s1;
        }
    }
}

// ---- kern3: reduce cent2 partials ([chb][pos][f][o]), squash, store. ----------
// R8/R10-proven structure: 576 blocks x 256 threads. Thread t covers
// (f,q) = ((t&127)>>2, t&3) and 8 of 16 chunks (half = t>>7). Halves meet via
// 2 KB LDS + 1 barrier; squash via 2 shfl within the 4-lane o-group.
__global__ __launch_bounds__(256) void kern3(const float* __restrict__ part2,
                                             float* __restrict__ out)
{
    __shared__ float4 red[128];

    const int tid  = threadIdx.x;
    const int pos  = blockIdx.x;              // 0..575
    const int half = tid >> 7;                // chunks 0..7 / 8..15
    const int slot = tid & 127;               // (f,q)
    const int f = slot >> 2, q = slot & 3;

    float ax=0.f, ay=0.f, az=0.f, aw=0.f;
    #pragma unroll
    for (int k = 0; k < CHB/2; ++k) {
        const int kk = half*(CHB/2) + k;
        const float4 v = *(const float4*)(part2 + ((size_t)(kk*NPOS + pos)*F + f)*DO + q*4);
        ax += v.x; ay += v.y; az += v.z; aw += v.w;
    }
    if (half) { float4 r; r.x=ax; r.y=ay; r.z=az; r.w=aw; red[slot] = r; }
    __syncthreads();
    if (!half) {
        const float4 o = red[slot];
        ax += o.x; ay += o.y; az += o.z; aw += o.w;

        float sq = ax*ax + ay*ay + az*az + aw*aw;
        sq += __shfl_xor(sq, 1);
        sq += __shfl_xor(sq, 2);              // full 16-o norm within 4-lane group
        const float sc = (sq/(1.f + sq)) * rsqrtf(sq + EPS);

        float4 s; s.x=ax*sc; s.y=ay*sc; s.z=az*sc; s.w=aw*sc;
        *(float4*)(out + ((size_t)pos*F + f)*DO + q*4) = s;
    }
}

// -------- fp32 single-kernel fallback (only if ws too small) -------------------
__device__ __forceinline__ float dot8(const float4* __restrict__ w,
                                      const float4 p0, const float4 p1) {
    float4 a = w[0], b = w[1];
    return a.x*p0.x + a.y*p0.y + a.z*p0.z + a.w*p0.w
         + b.x*p1.x + b.y*p1.y + b.z*p1.z + b.w*p1.w;
}

__global__ __launch_bounds__(256) void capsule_kernel_f32(
    const float* __restrict__ x, const float* __restrict__ Wt,
    float* __restrict__ out)
{
    __shared__ float patch[C*DI];
    __shared__ float cent[F*DO];
    __shared__ float out1[F*DO];
    __shared__ float agr[F*C];
    __shared__ float scale_s[F];

    const int tid = threadIdx.x;
    const int pos = blockIdx.x;
    const int b   = pos / (HO*WO);
    const int rem = pos % (HO*WO);
    const int ho  = rem / WO;
    const int wo  = rem % WO;

    #pragma unroll
    for (int slab = 0; slab < 9; ++slab) {
        const int kh = slab / 3, kw = slab % 3;
        const float* src = x + (((b*H_IN + ho + kh)*W_IN + (wo + kw))*FIN)*DI;
        patch[slab*256 + tid] = src[tid];
    }
    __syncthreads();

    const float4* pv = (const float4*)patch;

    {
        const int fo0 = tid, fo1 = tid + 256;
        const int f0 = fo0 >> 4, o0 = fo0 & 15;
        const int f1 = fo1 >> 4, o1 = fo1 & 15;
        float acc0 = 0.f, acc1 = 0.f;
        for (int c = 0; c < C; ++c) {
            const float4 p0 = pv[c*2], p1 = pv[c*2+1];
            acc0 += dot8((const float4*)(Wt + ((f0*C + c)*DO + o0)*DI), p0, p1);
            acc1 += dot8((const float4*)(Wt + ((f1*C + c)*DO + o1)*DI), p0, p1);
        }
        cent[fo0] = acc0 * (1.f/32.f);
        cent[fo1] = acc1 * (1.f/32.f);
    }
    __syncthreads();

    if (tid < F) {
        float sn = 0.f;
        #pragma unroll
        for (int o = 0; o < DO; ++o) { float v = cent[tid*DO + o]; sn += v*v; }
        const float sc = (sn/(1.f + sn)) * rsqrtf(sn + EPS);
        #pragma unroll
        for (int o = 0; o < DO; ++o) out1[tid*DO + o] = cent[tid*DO + o] * sc;
    }
    __syncthreads();

    #pragma unroll 1
    for (int r = 0; r < (F*C)/256; ++r) {
        const int pp = tid + 256*r;
        const int f = pp / C, c = pp % C;
        const float4* wrow = (const float4*)(Wt + (f*C + c)*DO*DI);
        const float4 p0 = pv[c*2], p1 = pv[c*2+1];
        float a = 0.f;
        #pragma unroll
        for (int o = 0; o < DO; ++o) a += dot8(wrow + o*2, p0, p1) * out1[f*DO + o];
        agr[pp] = a;
    }
    __syncthreads();

    for (int c = tid; c < C; c += 256) {
        float m = -1e30f;
        #pragma unroll
        for (int f = 0; f < F; ++f) m = fmaxf(m, agr[f*C + c]);
        float s = 0.f;
        #pragma unroll
        for (int f = 0; f < F; ++f) {
            const float e = __expf(agr[f*C + c] - m);
            agr[f*C + c] = e; s += e;
        }
        const float inv = 1.f / s;
        #pragma unroll
        for (int f = 0; f < F; ++f) agr[f*C + c] *= inv;
    }
    __syncthreads();

    {
        const int fo0 = tid, fo1 = tid + 256;
        const int f0 = fo0 >> 4, o0 = fo0 & 15;
        const int f1 = fo1 >> 4, o1 = fo1 & 15;
        float acc0 = 0.f, acc1 = 0.f;
        for (int c = 0; c < C; ++c) {
            const float4 p0 = pv[c*2], p1 = pv[c*2+1];
            acc0 += agr[f0*C + c] * dot8((const float4*)(Wt + ((f0*C + c)*DO + o0)*DI), p0, p1);
            acc1 += agr[f1*C + c] * dot8((const float4*)(Wt + ((f1*C + c)*DO + o1)*DI), p0, p1);
        }
        cent[fo0] = acc0;
        cent[fo1] = acc1;
    }
    __syncthreads();

    if (tid < F) {
        float sn = 0.f;
        #pragma unroll
        for (int o = 0; o < DO; ++o) { float v = cent[tid*DO + o]; sn += v*v; }
        scale_s[tid] = (sn/(1.f + sn)) * rsqrtf(sn + EPS);
    }
    __syncthreads();

    out[pos*(F*DO) + tid]       = cent[tid]       * scale_s[tid >> 4];
    out[pos*(F*DO) + tid + 256] = cent[tid + 256] * scale_s[(tid >> 4) + 16];
}

extern "C" void kernel_launch(void* const* d_in, const int* in_sizes, int n_in,
                              void* d_out, int out_size, void* d_ws, size_t ws_size,
                              hipStream_t stream) {
    const float* x  = (const float*)d_in[0];
    const float* Wt = (const float*)d_in[1];
    float* out = (float*)d_out;

    if (ws_size >= W2H_BYTES + WH_BYTES + PH_BYTES + PART_BYTES + OUT1P_BYTES) {
        char* p = (char*)d_ws;
        unsigned short* W2h = (unsigned short*)p;            p += W2H_BYTES;
        unsigned short* Wh  = (unsigned short*)p;            p += WH_BYTES;
        unsigned short* Ph  = (unsigned short*)p;            p += PH_BYTES;
        float* part = (float*)p;                             p += PART_BYTES;
        float* out1p = (float*)p;

        kernConv<<<CVT_GRID, 256, 0, stream>>>(Wt, x, W2h, Wh, Ph);  // 1224 blocks
        kernM1<<<36*8*2, 256, 0, stream>>>(Ph, Wh, out1p);           // 576 blocks, split-K
        kern2w<<<GRID2, 512, 0, stream>>>(Ph, W2h, out1p, part);     // 1152 blocks, 8 waves
        kern3<<<NPOS, 256, 0, stream>>>(part, out);                  // 576 blocks, 4 waves
    } else {
        capsule_kernel_f32<<<NPOS, 256, 0, stream>>>(x, Wt, out);
    }
}

// Round 12
// 125.042 us; speedup vs baseline: 1.0600x; 1.0600x over previous
//
#include <hip/hip_runtime.h>

#define NB   4
#define H_IN 14
#define W_IN 14
#define FIN  32
#define DI   8
#define F    32
#define C    288   // 3*3*32
#define DO   16
#define HO   12
#define WO   12
#define NPOS (NB*HO*WO)   // 576
#define EPS  1e-7f

#define CH   16            // c-chunks
#define CC   (C/CH)        // 18
#define GP   2             // positions per WAVE (R3/R7-proven sweet spot)
#define GRID2 ((CH*NPOS/GP)/4) // 1152 blocks, 4 autonomous waves each

#define KTOT  (C*DI)       // 2304 = K of the cent1 GEMM
#define KHALF 1152         // K/2 per kernM1 block (split-K)
#define KPADH 1156         // LDS row pad: 578 words % 32 = 2 -> 2-way (free)

#define W2H_BYTES  ((size_t)F*C*DO*DI*2)       // 2,359,296  (transposed, kern2)
#define WH_BYTES   ((size_t)F*C*DO*DI*2)       // 2,359,296  (orig layout, MFMA B)
#define PH_BYTES   ((size_t)NPOS*KTOT*2)       // 2,654,208  (patch matrix fp16)
#define PART_BYTES ((size_t)CH*NPOS*F*DO*4)    // 18,874,368 (part2 fp32, [ch][pos][f][o])
#define OUT1P_BYTES ((size_t)2*NPOS*F*DO*4)    // 2,359,296  (K-half partials, pre-squash)

#define CVT_W   576        // fused W2h+Wh blocks (single Wt read)
#define CVT_PH  648        // 165888 uint4
#define CVT_GRID (CVT_W + CVT_PH)

typedef _Float16 h2 __attribute__((ext_vector_type(2)));
typedef _Float16 h8v __attribute__((ext_vector_type(8)));
typedef float    f4v __attribute__((ext_vector_type(4)));

__device__ __forceinline__ unsigned int pack2(float a, float b) {
    h2 v; v.x = (_Float16)a; v.y = (_Float16)b;
    return __builtin_bit_cast(unsigned int, v);
}

// 8-term fp16 dot with fp32 accumulate
__device__ __forceinline__ float dot8h(const uint4 w, const uint4 v, float acc) {
#if __has_builtin(__builtin_amdgcn_fdot2)
    acc = __builtin_amdgcn_fdot2(__builtin_bit_cast(h2, w.x), __builtin_bit_cast(h2, v.x), acc, false);
    acc = __builtin_amdgcn_fdot2(__builtin_bit_cast(h2, w.y), __builtin_bit_cast(h2, v.y), acc, false);
    acc = __builtin_amdgcn_fdot2(__builtin_bit_cast(h2, w.z), __builtin_bit_cast(h2, v.z), acc, false);
    acc = __builtin_amdgcn_fdot2(__builtin_bit_cast(h2, w.w), __builtin_bit_cast(h2, v.w), acc, false);
#else
    const h2 w0 = __builtin_bit_cast(h2, w.x), v0 = __builtin_bit_cast(h2, v.x);
    const h2 w1 = __builtin_bit_cast(h2, w.y), v1 = __builtin_bit_cast(h2, v.y);
    const h2 w2 = __builtin_bit_cast(h2, w.z), v2 = __builtin_bit_cast(h2, v.z);
    const h2 w3 = __builtin_bit_cast(h2, w.w), v3 = __builtin_bit_cast(h2, v.w);
    acc += (float)w0.x*(float)v0.x + (float)w0.y*(float)v0.y
         + (float)w1.x*(float)v1.x + (float)w1.y*(float)v1.y
         + (float)w2.x*(float)v2.x + (float)w2.y*(float)v2.y
         + (float)w3.x*(float)v3.x + (float)w3.y*(float)v3.y;
#endif
    return acc;
}

__device__ __forceinline__ int xbase_of(int pos) {
    const int b = pos/(HO*WO), rem = pos%(HO*WO), ho = rem/WO, wo = rem%WO;
    return ((b*H_IN + ho)*W_IN + wo)*FIN*DI;
}

__device__ __forceinline__ int coff_of(int c) {
    const int slab = c >> 5, fin = c & 31;
    const int kh = slab/3, kw = slab%3;
    return (kh*W_IN + kw)*FIN*DI + fin*DI;
}

// ---- conversion (single Wt read feeds BOTH Wh and W2h) ------------------------
__global__ __launch_bounds__(256) void kernConv(const float* __restrict__ Wt,
                                                const float* __restrict__ x,
                                                unsigned short* __restrict__ W2h,
                                                unsigned short* __restrict__ Wh,
                                                unsigned short* __restrict__ Ph) {
    const int b = blockIdx.x;
    if (b < CVT_W) {                   // one coalesced Wt read -> Wh copy + W2h transpose
        const int idx = b*256 + threadIdx.x;       // linear over Wt rows (f*C+c)*DO+o
        const float* src = Wt + (size_t)idx*8;     // coalesced read
        const float4 a = *(const float4*)src;
        const float4 bb = *(const float4*)(src + 4);
        uint4 r;
        r.x = pack2(a.x, a.y);   r.y = pack2(a.z, a.w);
        r.z = pack2(bb.x, bb.y); r.w = pack2(bb.z, bb.w);
        ((uint4*)Wh)[idx] = r;                         // same-layout copy
        const int o = idx & 15;
        const int c = (idx >> 4) % C;
        const int f = idx / (C*DO);
        ((uint4*)W2h)[(size_t)(c*DO + o)*F + f] = r;   // scattered write (L2 absorbs)
    } else {                           // Ph[pos][c*8+i]
        const int pc = (b - CVT_W)*256 + threadIdx.x;  // 165888
        const int pos = pc / C, c = pc % C;
        const float* src = x + xbase_of(pos) + coff_of(c);
        const float4 a = *(const float4*)src;
        const float4 bb = *(const float4*)(src + 4);
        uint4 r;
        r.x = pack2(a.x, a.y);   r.y = pack2(a.z, a.w);
        r.z = pack2(bb.x, bb.y); r.w = pack2(bb.z, bb.w);
        ((uint4*)Ph)[pc] = r;
    }
}

// ---- kernM1: cent1 GEMM via MFMA -> raw K-half partials (R7-proven split-K). --
__global__ __launch_bounds__(256) void kernM1(const unsigned short* __restrict__ Ph,
                                              const unsigned short* __restrict__ Wh,
                                              float* __restrict__ out1p)
{
    __shared__ unsigned short As[16][KPADH];      // 36,992 B

    const int tid  = threadIdx.x;
    const int lane = tid & 63;
    const int wv   = tid >> 6;                    // 0..3
    const int ks   = blockIdx.x & 1;              // K-half
    const int fg   = (blockIdx.x >> 1) & 7;       // 0..7
    const int pt   = blockIdx.x >> 4;             // 0..35
    const int f    = wv*8 + fg;                   // all 32 f covered
    const int pos0 = pt*16;
    const int n    = lane & 15, q = lane >> 4;

    // stage half-K A-tile: 2304 uint4, 9 per thread, coalesced
    #pragma unroll
    for (int r = 0; r < 9; ++r) {
        const int linear = r*256 + tid;
        const int row = linear / 144, col = linear % 144;   // 144 uint4 per row
        const uint4 v = *(const uint4*)(Ph + (size_t)(pos0 + row)*KTOT + ks*KHALF + col*8);
        *(uint4*)&As[row][col*8] = v;
    }
    __syncthreads();

    const unsigned short* pa = &As[n][q*8];                                 // A: m=lane&15
    const unsigned short* pb = Wh + ((size_t)(f*C + ks*144 + q)*DO + n)*DI; // B: n=lane&15

    f4v acc0 = {0.f,0.f,0.f,0.f}, acc1 = {0.f,0.f,0.f,0.f};
    #pragma unroll 4
    for (int s = 0; s < 36; s += 2) {             // 18 steps, 2 chains
        const h8v a0 = *(const h8v*)(pa + s*32);
        const h8v b0 = *(const h8v*)(pb + (size_t)s*4*DO*DI);
        const h8v a1 = *(const h8v*)(pa + (s+1)*32);
        const h8v b1 = *(const h8v*)(pb + (size_t)(s+1)*4*DO*DI);
        acc0 = __builtin_amdgcn_mfma_f32_16x16x32_f16(a0, b0, acc0, 0, 0, 0);
        acc1 = __builtin_amdgcn_mfma_f32_16x16x32_f16(a1, b1, acc1, 0, 0, 0);
    }

    // write raw partials (no reduction, no squash)
    #pragma unroll
    for (int r = 0; r < 4; ++r) {
        out1p[((size_t)ks*NPOS + pos0 + q*4 + r)*512 + f*DO + n] = acc0[r] + acc1[r];
    }
}

// ---- kern2w: wave-autonomous routing iteration 2 (R10 body + unroll 2). -------
// 64 lanes = 32 f (lane&31) x 2 o-groups (lane>>5, 8 o each); GP=2 pos/wave.
// R12: cl-loop unroll 2 -- two independent (pos,c) instance streams interleave
// in-flight, so instance B's W2h loads/dots issue under instance A's serial
// shfl-softmax chain (ILP, not TLP -- wave count is exonerated by R4/R8/R11).
// Prologue: u = squash((out1p[0]+out1p[1])/32). NO-MAX softmax. ZERO barriers,
// ZERO LDS. Everything else R10-verbatim.
// writes part2[ch][pos][f][o] fp32
__global__ __launch_bounds__(256) void kern2w(const unsigned short* __restrict__ Ph,
                                              const unsigned short* __restrict__ W2h,
                                              const float* __restrict__ out1p,
                                              float* __restrict__ part2)
{
    const int tid  = threadIdx.x;
    const int lane = tid & 63;
    const int wv   = tid >> 6;                // 0..3 (autonomous)
    const int f    = lane & 31;
    const int og   = lane >> 5;               // 0/1
    const int o0   = og*8;

    const int ch   = blockIdx.x & (CH-1);     // all 4 waves share ch
    const int gq   = blockIdx.x >> 4;         // 0..71
    const int grp  = __builtin_amdgcn_readfirstlane(gq*4 + wv);  // wave-uniform
    const int pos0 = grp*GP;

    const int c0 = ch*CC;
    const uint4* W2h4 = (const uint4*)W2h;

    // u[k][p] = squash(cent1)[pos][f][o0+k], cent1 = (half0+half1)/32
    float u[8][GP];
    #pragma unroll
    for (int p = 0; p < GP; ++p) {
        const float* up0 = out1p + (size_t)(pos0 + p)*512 + f*DO + o0;
        const float* up1 = up0 + (size_t)NPOS*512;
        const float4 a0 = *(const float4*)up0;
        const float4 b0 = *(const float4*)(up0 + 4);
        const float4 a1 = *(const float4*)up1;
        const float4 b1 = *(const float4*)(up1 + 4);
        float ur[8];
        ur[0]=(a0.x+a1.x)*(1.f/32.f); ur[1]=(a0.y+a1.y)*(1.f/32.f);
        ur[2]=(a0.z+a1.z)*(1.f/32.f); ur[3]=(a0.w+a1.w)*(1.f/32.f);
        ur[4]=(b0.x+b1.x)*(1.f/32.f); ur[5]=(b0.y+b1.y)*(1.f/32.f);
        ur[6]=(b0.z+b1.z)*(1.f/32.f); ur[7]=(b0.w+b1.w)*(1.f/32.f);
        float sq = 0.f;
        #pragma unroll
        for (int k = 0; k < 8; ++k) sq += ur[k]*ur[k];
        sq += __shfl_xor(sq, 32);             // full 16-o norm
        const float sc = (sq/(1.f + sq)) * rsqrtf(sq + EPS);
        #pragma unroll
        for (int k = 0; k < 8; ++k) u[k][p] = ur[k]*sc;
    }

    float acc[8][GP];
    #pragma unroll
    for (int k = 0; k < 8; ++k)
        #pragma unroll
        for (int p = 0; p < GP; ++p) acc[k][p] = 0.f;

    #pragma unroll 2
    for (int cl = 0; cl < CC; ++cl) {
        const int c = c0 + cl;

        // patch vectors: wave-uniform -> scalar loads
        uint4 xv[GP];
        #pragma unroll
        for (int p = 0; p < GP; ++p)
            xv[p] = *(const uint4*)(Ph + (size_t)(pos0 + p)*KTOT + c*DI);

        // preds for my 8 o's, all GP positions
        float pred[8][GP];
        #pragma unroll
        for (int k = 0; k < 8; ++k) {
            const uint4 w = W2h4[(size_t)(c*DO + o0 + k)*F + f];
            #pragma unroll
            for (int p = 0; p < GP; ++p) pred[k][p] = dot8h(w, xv[p], 0.f);
        }

        // per position: agreement (o-sum via xor-32), NO-MAX softmax over f
        #pragma unroll
        for (int p = 0; p < GP; ++p) {
            float ap = 0.f;
            #pragma unroll
            for (int k = 0; k < 8; ++k) ap += pred[k][p]*u[k][p];
            ap += __shfl_xor(ap, 32);          // both halves now hold full agr

            const float e = __expf(ap);        // |ap| small: safe without max-sub
            float s = e;
            s += __shfl_xor(s, 1);
            s += __shfl_xor(s, 2);
            s += __shfl_xor(s, 4);
            s += __shfl_xor(s, 8);
            s += __shfl_xor(s, 16);
            const float cc = e / s;

            #pragma unroll
            for (int k = 0; k < 8; ++k) acc[k][p] += cc*pred[k][p];
        }
    }

    // store: [ch][pos][f][o], per-thread 8 contiguous floats = 2 float4
    #pragma unroll
    for (int p = 0; p < GP; ++p) {
        float* dst = part2 + ((size_t)(ch*NPOS + pos0 + p)*F + f)*DO + o0;
        float4 s0, s1;
        s0.x=acc[0][p]; s0.y=acc[1][p]; s0.z=acc[2][p]; s0.w=acc[3][p];
        s1.x=acc[4][p]; s1.y=acc[5][p]; s1.z=acc[6][p]; s1.w=acc[7][p];
        *(float4*)dst = s0;
        *(float4*)(dst + 4) = s1;
    }
}

// ---- kern3: reduce cent2 partials ([ch][pos][f][o]), squash, store. -----------
// R8/R10-proven structure: 576 blocks x 256 threads. Thread t covers
// (f,q) = ((t&127)>>2, t&3) and 8 of 16 ch (half = t>>7). Halves meet via
// 2 KB LDS + 1 barrier; squash via 2 shfl within the 4-lane o-group.
__global__ __launch_bounds__(256) void kern3(const float* __restrict__ part2,
                                             float* __restrict__ out)
{
    __shared__ float4 red[128];

    const int tid  = threadIdx.x;
    const int pos  = blockIdx.x;              // 0..575
    const int half = tid >> 7;                // ch 0..7 / 8..15
    const int slot = tid & 127;               // (f,q)
    const int f = slot >> 2, q = slot & 3;

    float ax=0.f, ay=0.f, az=0.f, aw=0.f;
    #pragma unroll
    for (int k = 0; k < CH/2; ++k) {
        const int kk = half*(CH/2) + k;
        const float4 v = *(const float4*)(part2 + ((size_t)(kk*NPOS + pos)*F + f)*DO + q*4);
        ax += v.x; ay += v.y; az += v.z; aw += v.w;
    }
    if (half) { float4 r; r.x=ax; r.y=ay; r.z=az; r.w=aw; red[slot] = r; }
    __syncthreads();
    if (!half) {
        const float4 o = red[slot];
        ax += o.x; ay += o.y; az += o.z; aw += o.w;

        float sq = ax*ax + ay*ay + az*az + aw*aw;
        sq += __shfl_xor(sq, 1);
        sq += __shfl_xor(sq, 2);              // full 16-o norm within 4-lane group
        const float sc = (sq/(1.f + sq)) * rsqrtf(sq + EPS);

        float4 s; s.x=ax*sc; s.y=ay*sc; s.z=az*sc; s.w=aw*sc;
        *(float4*)(out + ((size_t)pos*F + f)*DO + q*4) = s;
    }
}

// -------- fp32 single-kernel fallback (only if ws too small) -------------------
__device__ __forceinline__ float dot8(const float4* __restrict__ w,
                                      const float4 p0, const float4 p1) {
    float4 a = w[0], b = w[1];
    return a.x*p0.x + a.y*p0.y + a.z*p0.z + a.w*p0.w
         + b.x*p1.x + b.y*p1.y + b.z*p1.z + b.w*p1.w;
}

__global__ __launch_bounds__(256) void capsule_kernel_f32(
    const float* __restrict__ x, const float* __restrict__ Wt,
    float* __restrict__ out)
{
    __shared__ float patch[C*DI];
    __shared__ float cent[F*DO];
    __shared__ float out1[F*DO];
    __shared__ float agr[F*C];
    __shared__ float scale_s[F];

    const int tid = threadIdx.x;
    const int pos = blockIdx.x;
    const int b   = pos / (HO*WO);
    const int rem = pos % (HO*WO);
    const int ho  = rem / WO;
    const int wo  = rem % WO;

    #pragma unroll
    for (int slab = 0; slab < 9; ++slab) {
        const int kh = slab / 3, kw = slab % 3;
        const float* src = x + (((b*H_IN + ho + kh)*W_IN + (wo + kw))*FIN)*DI;
        patch[slab*256 + tid] = src[tid];
    }
    __syncthreads();

    const float4* pv = (const float4*)patch;

    {
        const int fo0 = tid, fo1 = tid + 256;
        const int f0 = fo0 >> 4, o0 = fo0 & 15;
        const int f1 = fo1 >> 4, o1 = fo1 & 15;
        float acc0 = 0.f, acc1 = 0.f;
        for (int c = 0; c < C; ++c) {
            const float4 p0 = pv[c*2], p1 = pv[c*2+1];
            acc0 += dot8((const float4*)(Wt + ((f0*C + c)*DO + o0)*DI), p0, p1);
            acc1 += dot8((const float4*)(Wt + ((f1*C + c)*DO + o1)*DI), p0, p1);
        }
        cent[fo0] = acc0 * (1.f/32.f);
        cent[fo1] = acc1 * (1.f/32.f);
    }
    __syncthreads();

    if (tid < F) {
        float sn = 0.f;
        #pragma unroll
        for (int o = 0; o < DO; ++o) { float v = cent[tid*DO + o]; sn += v*v; }
        const float sc = (sn/(1.f + sn)) * rsqrtf(sn + EPS);
        #pragma unroll
        for (int o = 0; o < DO; ++o) out1[tid*DO + o] = cent[tid*DO + o] * sc;
    }
    __syncthreads();

    #pragma unroll 1
    for (int r = 0; r < (F*C)/256; ++r) {
        const int pp = tid + 256*r;
        const int f = pp / C, c = pp % C;
        const float4* wrow = (const float4*)(Wt + (f*C + c)*DO*DI);
        const float4 p0 = pv[c*2], p1 = pv[c*2+1];
        float a = 0.f;
        #pragma unroll
        for (int o = 0; o < DO; ++o) a += dot8(wrow + o*2, p0, p1) * out1[f*DO + o];
        agr[pp] = a;
    }
    __syncthreads();

    for (int c = tid; c < C; c += 256) {
        float m = -1e30f;
        #pragma unroll
        for (int f = 0; f < F; ++f) m = fmaxf(m, agr[f*C + c]);
        float s = 0.f;
        #pragma unroll
        for (int f = 0; f < F; ++f) {
            const float e = __expf(agr[f*C + c] - m);
            agr[f*C + c] = e; s += e;
        }
        const float inv = 1.f / s;
        #pragma unroll
        for (int f = 0; f < F; ++f) agr[f*C + c] *= inv;
    }
    __syncthreads();

    {
        const int fo0 = tid, fo1 = tid + 256;
        const int f0 = fo0 >> 4, o0 = fo0 & 15;
        const int f1 = fo1 >> 4, o1 = fo1 & 15;
        float acc0 = 0.f, acc1 = 0.f;
        for (int c = 0; c < C; ++c) {
            const float4 p0 = pv[c*2], p1 = pv[c*2+1];
            acc0 += agr[f0*C + c] * dot8((const float4*)(Wt + ((f0*C + c)*DO + o0)*DI), p0, p1);
            acc1 += agr[f1*C + c] * dot8((const float4*)(Wt + ((f1*C + c)*DO + o1)*DI), p0, p1);
        }
        cent[fo0] = acc0;
        cent[fo1] = acc1;
    }
    __syncthreads();

    if (tid < F) {
        float sn = 0.f;
        #pragma unroll
        for (int o = 0; o < DO; ++o) { float v = cent[tid*DO + o]; sn += v*v; }
        scale_s[tid] = (sn/(1.f + sn)) * rsqrtf(sn + EPS);
    }
    __syncthreads();

    out[pos*(F*DO) + tid]       = cent[tid]       * scale_s[tid >> 4];
    out[pos*(F*DO) + tid + 256] = cent[tid + 256] * scale_s[(tid >> 4) + 16];
}

extern "C" void kernel_launch(void* const* d_in, const int* in_sizes, int n_in,
                              void* d_out, int out_size, void* d_ws, size_t ws_size,
                              hipStream_t stream) {
    const float* x  = (const float*)d_in[0];
    const float* Wt = (const float*)d_in[1];
    float* out = (float*)d_out;

    if (ws_size >= W2H_BYTES + WH_BYTES + PH_BYTES + PART_BYTES + OUT1P_BYTES) {
        char* p = (char*)d_ws;
        unsigned short* W2h = (unsigned short*)p;            p += W2H_BYTES;
        unsigned short* Wh  = (unsigned short*)p;            p += WH_BYTES;
        unsigned short* Ph  = (unsigned short*)p;            p += PH_BYTES;
        float* part = (float*)p;                             p += PART_BYTES;
        float* out1p = (float*)p;

        kernConv<<<CVT_GRID, 256, 0, stream>>>(Wt, x, W2h, Wh, Ph);  // 1224 blocks
        kernM1<<<36*8*2, 256, 0, stream>>>(Ph, Wh, out1p);           // 576 blocks, split-K
        kern2w<<<GRID2, 256, 0, stream>>>(Ph, W2h, out1p, part);     // 1152 blocks
        kern3<<<NPOS, 256, 0, stream>>>(part, out);                  // 576 blocks, 4 waves
    } else {
        capsule_kernel_f32<<<NPOS, 256, 0, stream>>>(x, Wt, out);
    }
}

// Round 13
// 118.899 us; speedup vs baseline: 1.1148x; 1.0517x over previous
//
#include <hip/hip_runtime.h>

#define NB   4
#define H_IN 14
#define W_IN 14
#define FIN  32
#define DI   8
#define F    32
#define C    288   // 3*3*32
#define DO   16
#define HO   12
#define WO   12
#define NPOS (NB*HO*WO)   // 576
#define EPS  1e-7f

#define CH   16            // c-chunks
#define CC   (C/CH)        // 18
#define GP   2             // positions per WAVE (R3/R7-proven sweet spot)
#define GRID2 ((CH*NPOS/GP)/4) // 1152 blocks, 4 autonomous waves each

#define KTOT  (C*DI)       // 2304 = K of the cent1 GEMM
#define KHALF 1152         // K/2 per kernM1 block (split-K)
#define KPADH 1156         // LDS row pad: 578 words % 32 = 2 -> 2-way (free)

#define W2H_BYTES  ((size_t)F*C*DO*DI*2)       // 2,359,296  (transposed, kern2)
#define WH_BYTES   ((size_t)F*C*DO*DI*2)       // 2,359,296  (orig layout, MFMA B)
#define PH_BYTES   ((size_t)NPOS*KTOT*2)       // 2,654,208  (patch matrix fp16)
#define PART_BYTES ((size_t)CH*NPOS*F*DO*2)    // 9,437,184  (part2 FP16, [ch][pos][f][o])
#define OUT1P_BYTES ((size_t)2*NPOS*F*DO*4)    // 2,359,296  (K-half partials, pre-squash)

#define CVT_W   576        // fused W2h+Wh blocks (single Wt read)
#define CVT_PH  648        // 165888 uint4
#define CVT_GRID (CVT_W + CVT_PH)

typedef _Float16 h2 __attribute__((ext_vector_type(2)));
typedef _Float16 h8v __attribute__((ext_vector_type(8)));
typedef float    f4v __attribute__((ext_vector_type(4)));

__device__ __forceinline__ unsigned int pack2(float a, float b) {
    h2 v; v.x = (_Float16)a; v.y = (_Float16)b;
    return __builtin_bit_cast(unsigned int, v);
}

__device__ __forceinline__ float2 unpack2(unsigned int u) {
    const h2 v = __builtin_bit_cast(h2, u);
    float2 r; r.x = (float)v.x; r.y = (float)v.y;
    return r;
}

// 8-term fp16 dot with fp32 accumulate
__device__ __forceinline__ float dot8h(const uint4 w, const uint4 v, float acc) {
#if __has_builtin(__builtin_amdgcn_fdot2)
    acc = __builtin_amdgcn_fdot2(__builtin_bit_cast(h2, w.x), __builtin_bit_cast(h2, v.x), acc, false);
    acc = __builtin_amdgcn_fdot2(__builtin_bit_cast(h2, w.y), __builtin_bit_cast(h2, v.y), acc, false);
    acc = __builtin_amdgcn_fdot2(__builtin_bit_cast(h2, w.z), __builtin_bit_cast(h2, v.z), acc, false);
    acc = __builtin_amdgcn_fdot2(__builtin_bit_cast(h2, w.w), __builtin_bit_cast(h2, v.w), acc, false);
#else
    const h2 w0 = __builtin_bit_cast(h2, w.x), v0 = __builtin_bit_cast(h2, v.x);
    const h2 w1 = __builtin_bit_cast(h2, w.y), v1 = __builtin_bit_cast(h2, v.y);
    const h2 w2 = __builtin_bit_cast(h2, w.z), v2 = __builtin_bit_cast(h2, v.z);
    const h2 w3 = __builtin_bit_cast(h2, w.w), v3 = __builtin_bit_cast(h2, v.w);
    acc += (float)w0.x*(float)v0.x + (float)w0.y*(float)v0.y
         + (float)w1.x*(float)v1.x + (float)w1.y*(float)v1.y
         + (float)w2.x*(float)v2.x + (float)w2.y*(float)v2.y
         + (float)w3.x*(float)v3.x + (float)w3.y*(float)v3.y;
#endif
    return acc;
}

__device__ __forceinline__ int xbase_of(int pos) {
    const int b = pos/(HO*WO), rem = pos%(HO*WO), ho = rem/WO, wo = rem%WO;
    return ((b*H_IN + ho)*W_IN + wo)*FIN*DI;
}

__device__ __forceinline__ int coff_of(int c) {
    const int slab = c >> 5, fin = c & 31;
    const int kh = slab/3, kw = slab%3;
    return (kh*W_IN + kw)*FIN*DI + fin*DI;
}

// ---- conversion (single Wt read feeds BOTH Wh and W2h) ------------------------
__global__ __launch_bounds__(256) void kernConv(const float* __restrict__ Wt,
                                                const float* __restrict__ x,
                                                unsigned short* __restrict__ W2h,
                                                unsigned short* __restrict__ Wh,
                                                unsigned short* __restrict__ Ph) {
    const int b = blockIdx.x;
    if (b < CVT_W) {                   // one coalesced Wt read -> Wh copy + W2h transpose
        const int idx = b*256 + threadIdx.x;       // linear over Wt rows (f*C+c)*DO+o
        const float* src = Wt + (size_t)idx*8;     // coalesced read
        const float4 a = *(const float4*)src;
        const float4 bb = *(const float4*)(src + 4);
        uint4 r;
        r.x = pack2(a.x, a.y);   r.y = pack2(a.z, a.w);
        r.z = pack2(bb.x, bb.y); r.w = pack2(bb.z, bb.w);
        ((uint4*)Wh)[idx] = r;                         // same-layout copy
        const int o = idx & 15;
        const int c = (idx >> 4) % C;
        const int f = idx / (C*DO);
        ((uint4*)W2h)[(size_t)(c*DO + o)*F + f] = r;   // scattered write (L2 absorbs)
    } else {                           // Ph[pos][c*8+i]
        const int pc = (b - CVT_W)*256 + threadIdx.x;  // 165888
        const int pos = pc / C, c = pc % C;
        const float* src = x + xbase_of(pos) + coff_of(c);
        const float4 a = *(const float4*)src;
        const float4 bb = *(const float4*)(src + 4);
        uint4 r;
        r.x = pack2(a.x, a.y);   r.y = pack2(a.z, a.w);
        r.z = pack2(bb.x, bb.y); r.w = pack2(bb.z, bb.w);
        ((uint4*)Ph)[pc] = r;
    }
}

// ---- kernM1: cent1 GEMM via MFMA -> raw K-half partials (R7-proven split-K). --
__global__ __launch_bounds__(256) void kernM1(const unsigned short* __restrict__ Ph,
                                              const unsigned short* __restrict__ Wh,
                                              float* __restrict__ out1p)
{
    __shared__ unsigned short As[16][KPADH];      // 36,992 B

    const int tid  = threadIdx.x;
    const int lane = tid & 63;
    const int wv   = tid >> 6;                    // 0..3
    const int ks   = blockIdx.x & 1;              // K-half
    const int fg   = (blockIdx.x >> 1) & 7;       // 0..7
    const int pt   = blockIdx.x >> 4;             // 0..35
    const int f    = wv*8 + fg;                   // all 32 f covered
    const int pos0 = pt*16;
    const int n    = lane & 15, q = lane >> 4;

    // stage half-K A-tile: 2304 uint4, 9 per thread, coalesced
    #pragma unroll
    for (int r = 0; r < 9; ++r) {
        const int linear = r*256 + tid;
        const int row = linear / 144, col = linear % 144;   // 144 uint4 per row
        const uint4 v = *(const uint4*)(Ph + (size_t)(pos0 + row)*KTOT + ks*KHALF + col*8);
        *(uint4*)&As[row][col*8] = v;
    }
    __syncthreads();

    const unsigned short* pa = &As[n][q*8];                                 // A: m=lane&15
    const unsigned short* pb = Wh + ((size_t)(f*C + ks*144 + q)*DO + n)*DI; // B: n=lane&15

    f4v acc0 = {0.f,0.f,0.f,0.f}, acc1 = {0.f,0.f,0.f,0.f};
    #pragma unroll 4
    for (int s = 0; s < 36; s += 2) {             // 18 steps, 2 chains
        const h8v a0 = *(const h8v*)(pa + s*32);
        const h8v b0 = *(const h8v*)(pb + (size_t)s*4*DO*DI);
        const h8v a1 = *(const h8v*)(pa + (s+1)*32);
        const h8v b1 = *(const h8v*)(pb + (size_t)(s+1)*4*DO*DI);
        acc0 = __builtin_amdgcn_mfma_f32_16x16x32_f16(a0, b0, acc0, 0, 0, 0);
        acc1 = __builtin_amdgcn_mfma_f32_16x16x32_f16(a1, b1, acc1, 0, 0, 0);
    }

    // write raw partials (no reduction, no squash)
    #pragma unroll
    for (int r = 0; r < 4; ++r) {
        out1p[((size_t)ks*NPOS + pos0 + q*4 + r)*512 + f*DO + n] = acc0[r] + acc1[r];
    }
}

// ---- kern2w: wave-autonomous routing iteration 2 (R10-verbatim body). ---------
// 64 lanes = 32 f (lane&31) x 2 o-groups (lane>>5, 8 o each); GP=2 pos/wave.
// Prologue: u = squash((out1p[0]+out1p[1])/32). NO-MAX softmax. ZERO barriers,
// ZERO LDS. R13: part2 stored as FP16 (uint4 of 8 halves per p) -- halves
// store traffic; fp16 rounding of partials adds ~1-3e-3 absmax (5x headroom).
// writes part2[ch][pos][f][o] fp16
__global__ __launch_bounds__(256) void kern2w(const unsigned short* __restrict__ Ph,
                                              const unsigned short* __restrict__ W2h,
                                              const float* __restrict__ out1p,
                                              unsigned short* __restrict__ part2)
{
    const int tid  = threadIdx.x;
    const int lane = tid & 63;
    const int wv   = tid >> 6;                // 0..3 (autonomous)
    const int f    = lane & 31;
    const int og   = lane >> 5;               // 0/1
    const int o0   = og*8;

    const int ch   = blockIdx.x & (CH-1);     // all 4 waves share ch
    const int gq   = blockIdx.x >> 4;         // 0..71
    const int grp  = __builtin_amdgcn_readfirstlane(gq*4 + wv);  // wave-uniform
    const int pos0 = grp*GP;

    const int c0 = ch*CC;
    const uint4* W2h4 = (const uint4*)W2h;

    // u[k][p] = squash(cent1)[pos][f][o0+k], cent1 = (half0+half1)/32
    float u[8][GP];
    #pragma unroll
    for (int p = 0; p < GP; ++p) {
        const float* up0 = out1p + (size_t)(pos0 + p)*512 + f*DO + o0;
        const float* up1 = up0 + (size_t)NPOS*512;
        const float4 a0 = *(const float4*)up0;
        const float4 b0 = *(const float4*)(up0 + 4);
        const float4 a1 = *(const float4*)up1;
        const float4 b1 = *(const float4*)(up1 + 4);
        float ur[8];
        ur[0]=(a0.x+a1.x)*(1.f/32.f); ur[1]=(a0.y+a1.y)*(1.f/32.f);
        ur[2]=(a0.z+a1.z)*(1.f/32.f); ur[3]=(a0.w+a1.w)*(1.f/32.f);
        ur[4]=(b0.x+b1.x)*(1.f/32.f); ur[5]=(b0.y+b1.y)*(1.f/32.f);
        ur[6]=(b0.z+b1.z)*(1.f/32.f); ur[7]=(b0.w+b1.w)*(1.f/32.f);
        float sq = 0.f;
        #pragma unroll
        for (int k = 0; k < 8; ++k) sq += ur[k]*ur[k];
        sq += __shfl_xor(sq, 32);             // full 16-o norm
        const float sc = (sq/(1.f + sq)) * rsqrtf(sq + EPS);
        #pragma unroll
        for (int k = 0; k < 8; ++k) u[k][p] = ur[k]*sc;
    }

    float acc[8][GP];
    #pragma unroll
    for (int k = 0; k < 8; ++k)
        #pragma unroll
        for (int p = 0; p < GP; ++p) acc[k][p] = 0.f;

    #pragma unroll 1
    for (int cl = 0; cl < CC; ++cl) {
        const int c = c0 + cl;

        // patch vectors: wave-uniform -> scalar loads
        uint4 xv[GP];
        #pragma unroll
        for (int p = 0; p < GP; ++p)
            xv[p] = *(const uint4*)(Ph + (size_t)(pos0 + p)*KTOT + c*DI);

        // preds for my 8 o's, all GP positions
        float pred[8][GP];
        #pragma unroll
        for (int k = 0; k < 8; ++k) {
            const uint4 w = W2h4[(size_t)(c*DO + o0 + k)*F + f];
            #pragma unroll
            for (int p = 0; p < GP; ++p) pred[k][p] = dot8h(w, xv[p], 0.f);
        }

        // per position: agreement (o-sum via xor-32), NO-MAX softmax over f
        #pragma unroll
        for (int p = 0; p < GP; ++p) {
            float ap = 0.f;
            #pragma unroll
            for (int k = 0; k < 8; ++k) ap += pred[k][p]*u[k][p];
            ap += __shfl_xor(ap, 32);          // both halves now hold full agr

            const float e = __expf(ap);        // |ap| small: safe without max-sub
            float s = e;
            s += __shfl_xor(s, 1);
            s += __shfl_xor(s, 2);
            s += __shfl_xor(s, 4);
            s += __shfl_xor(s, 8);
            s += __shfl_xor(s, 16);
            const float cc = e / s;

            #pragma unroll
            for (int k = 0; k < 8; ++k) acc[k][p] += cc*pred[k][p];
        }
    }

    // store: [ch][pos][f][o] fp16, per-thread 8 halves = 1 uint4 per p (coalesced)
    #pragma unroll
    for (int p = 0; p < GP; ++p) {
        unsigned short* dst = part2 + ((size_t)(ch*NPOS + pos0 + p)*F + f)*DO + o0;
        uint4 s;
        s.x = pack2(acc[0][p], acc[1][p]);
        s.y = pack2(acc[2][p], acc[3][p]);
        s.z = pack2(acc[4][p], acc[5][p]);
        s.w = pack2(acc[6][p], acc[7][p]);
        *(uint4*)dst = s;
    }
}

// ---- kern3: reduce fp16 cent2 partials ([ch][pos][f][o]), squash, store. ------
// R13: 576 blocks x 1 wave; lane = (f = lane&31, oh = lane>>5). Per ch: one
// uint4 load (8 halves), fp32 accumulate. Full 16-o norm via shfl_xor(32).
// Loads/stores fully coalesced (wave spans 2 KB contiguous per ch).
__global__ __launch_bounds__(64) void kern3(const unsigned short* __restrict__ part2,
                                            float* __restrict__ out)
{
    const int lane = threadIdx.x;             // 0..63
    const int pos  = blockIdx.x;              // 0..575
    const int f = lane & 31, oh = lane >> 5, o0 = oh*8;

    float a0=0.f,a1=0.f,a2=0.f,a3=0.f,a4=0.f,a5=0.f,a6=0.f,a7=0.f;
    #pragma unroll
    for (int k = 0; k < CH; ++k) {
        const uint4 v = *(const uint4*)(part2 + ((size_t)(k*NPOS + pos)*F + f)*DO + o0);
        const float2 p0 = unpack2(v.x), p1 = unpack2(v.y);
        const float2 p2 = unpack2(v.z), p3 = unpack2(v.w);
        a0 += p0.x; a1 += p0.y; a2 += p1.x; a3 += p1.y;
        a4 += p2.x; a5 += p2.y; a6 += p3.x; a7 += p3.y;
    }
    float sq = a0*a0 + a1*a1 + a2*a2 + a3*a3 + a4*a4 + a5*a5 + a6*a6 + a7*a7;
    sq += __shfl_xor(sq, 32);                 // full sum over 16 o
    const float sc = (sq/(1.f + sq)) * rsqrtf(sq + EPS);

    float* dst = out + ((size_t)pos*F + f)*DO + o0;
    float4 s0, s1;
    s0.x=a0*sc; s0.y=a1*sc; s0.z=a2*sc; s0.w=a3*sc;
    s1.x=a4*sc; s1.y=a5*sc; s1.z=a6*sc; s1.w=a7*sc;
    *(float4*)dst = s0;
    *(float4*)(dst + 4) = s1;
}

// -------- fp32 single-kernel fallback (only if ws too small) -------------------
__device__ __forceinline__ float dot8(const float4* __restrict__ w,
                                      const float4 p0, const float4 p1) {
    float4 a = w[0], b = w[1];
    return a.x*p0.x + a.y*p0.y + a.z*p0.z + a.w*p0.w
         + b.x*p1.x + b.y*p1.y + b.z*p1.z + b.w*p1.w;
}

__global__ __launch_bounds__(256) void capsule_kernel_f32(
    const float* __restrict__ x, const float* __restrict__ Wt,
    float* __restrict__ out)
{
    __shared__ float patch[C*DI];
    __shared__ float cent[F*DO];
    __shared__ float out1[F*DO];
    __shared__ float agr[F*C];
    __shared__ float scale_s[F];

    const int tid = threadIdx.x;
    const int pos = blockIdx.x;
    const int b   = pos / (HO*WO);
    const int rem = pos % (HO*WO);
    const int ho  = rem / WO;
    const int wo  = rem % WO;

    #pragma unroll
    for (int slab = 0; slab < 9; ++slab) {
        const int kh = slab / 3, kw = slab % 3;
        const float* src = x + (((b*H_IN + ho + kh)*W_IN + (wo + kw))*FIN)*DI;
        patch[slab*256 + tid] = src[tid];
    }
    __syncthreads();

    const float4* pv = (const float4*)patch;

    {
        const int fo0 = tid, fo1 = tid + 256;
        const int f0 = fo0 >> 4, o0 = fo0 & 15;
        const int f1 = fo1 >> 4, o1 = fo1 & 15;
        float acc0 = 0.f, acc1 = 0.f;
        for (int c = 0; c < C; ++c) {
            const float4 p0 = pv[c*2], p1 = pv[c*2+1];
            acc0 += dot8((const float4*)(Wt + ((f0*C + c)*DO + o0)*DI), p0, p1);
            acc1 += dot8((const float4*)(Wt + ((f1*C + c)*DO + o1)*DI), p0, p1);
        }
        cent[fo0] = acc0 * (1.f/32.f);
        cent[fo1] = acc1 * (1.f/32.f);
    }
    __syncthreads();

    if (tid < F) {
        float sn = 0.f;
        #pragma unroll
        for (int o = 0; o < DO; ++o) { float v = cent[tid*DO + o]; sn += v*v; }
        const float sc = (sn/(1.f + sn)) * rsqrtf(sn + EPS);
        #pragma unroll
        for (int o = 0; o < DO; ++o) out1[tid*DO + o] = cent[tid*DO + o] * sc;
    }
    __syncthreads();

    #pragma unroll 1
    for (int r = 0; r < (F*C)/256; ++r) {
        const int pp = tid + 256*r;
        const int f = pp / C, c = pp % C;
        const float4* wrow = (const float4*)(Wt + (f*C + c)*DO*DI);
        const float4 p0 = pv[c*2], p1 = pv[c*2+1];
        float a = 0.f;
        #pragma unroll
        for (int o = 0; o < DO; ++o) a += dot8(wrow + o*2, p0, p1) * out1[f*DO + o];
        agr[pp] = a;
    }
    __syncthreads();

    for (int c = tid; c < C; c += 256) {
        float m = -1e30f;
        #pragma unroll
        for (int f = 0; f < F; ++f) m = fmaxf(m, agr[f*C + c]);
        float s = 0.f;
        #pragma unroll
        for (int f = 0; f < F; ++f) {
            const float e = __expf(agr[f*C + c] - m);
            agr[f*C + c] = e; s += e;
        }
        const float inv = 1.f / s;
        #pragma unroll
        for (int f = 0; f < F; ++f) agr[f*C + c] *= inv;
    }
    __syncthreads();

    {
        const int fo0 = tid, fo1 = tid + 256;
        const int f0 = fo0 >> 4, o0 = fo0 & 15;
        const int f1 = fo1 >> 4, o1 = fo1 & 15;
        float acc0 = 0.f, acc1 = 0.f;
        for (int c = 0; c < C; ++c) {
            const float4 p0 = pv[c*2], p1 = pv[c*2+1];
            acc0 += agr[f0*C + c] * dot8((const float4*)(Wt + ((f0*C + c)*DO + o0)*DI), p0, p1);
            acc1 += agr[f1*C + c] * dot8((const float4*)(Wt + ((f1*C + c)*DO + o1)*DI), p0, p1);
        }
        cent[fo0] = acc0;
        cent[fo1] = acc1;
    }
    __syncthreads();

    if (tid < F) {
        float sn = 0.f;
        #pragma unroll
        for (int o = 0; o < DO; ++o) { float v = cent[tid*DO + o]; sn += v*v; }
        scale_s[tid] = (sn/(1.f + sn)) * rsqrtf(sn + EPS);
    }
    __syncthreads();

    out[pos*(F*DO) + tid]       = cent[tid]       * scale_s[tid >> 4];
    out[pos*(F*DO) + tid + 256] = cent[tid + 256] * scale_s[(tid >> 4) + 16];
}

extern "C" void kernel_launch(void* const* d_in, const int* in_sizes, int n_in,
                              void* d_out, int out_size, void* d_ws, size_t ws_size,
                              hipStream_t stream) {
    const float* x  = (const float*)d_in[0];
    const float* Wt = (const float*)d_in[1];
    float* out = (float*)d_out;

    if (ws_size >= W2H_BYTES + WH_BYTES + PH_BYTES + PART_BYTES + OUT1P_BYTES) {
        char* p = (char*)d_ws;
        unsigned short* W2h = (unsigned short*)p;            p += W2H_BYTES;
        unsigned short* Wh  = (unsigned short*)p;            p += WH_BYTES;
        unsigned short* Ph  = (unsigned short*)p;            p += PH_BYTES;
        unsigned short* part = (unsigned short*)p;           p += PART_BYTES;
        float* out1p = (float*)p;

        kernConv<<<CVT_GRID, 256, 0, stream>>>(Wt, x, W2h, Wh, Ph);  // 1224 blocks
        kernM1<<<36*8*2, 256, 0, stream>>>(Ph, Wh, out1p);           // 576 blocks, split-K
        kern2w<<<GRID2, 256, 0, stream>>>(Ph, W2h, out1p, part);     // 1152 blocks
        kern3<<<NPOS, 64, 0, stream>>>(part, out);                   // 576 blocks, 1 wave each
    } else {
        capsule_kernel_f32<<<NPOS, 256, 0, stream>>>(x, Wt, out);
    }
}